// Round 2
// baseline (1362.833 us; speedup 1.0000x reference)
//
#include <hip/hip_runtime.h>
#include <math.h>

#define C 16
#define CK 16
#define NP 5
#define RH 32
#define COUT 32
#define EPS 1e-8f
#define SCALE 0.35355339059327373f  // 1/sqrt(8)

// ---- order-preserving float<->uint for atomicMax-based segment max ----
static __device__ __forceinline__ unsigned fenc(float f) {
    unsigned u = __float_as_uint(f);
    return (u & 0x80000000u) ? ~u : (u | 0x80000000u);
}
static __device__ __forceinline__ float fdec(unsigned u) {
    u = (u & 0x80000000u) ? (u & 0x7fffffffu) : ~u;
    return __uint_as_float(u);
}

// ---------------- K1: per-node q projections ----------------
__global__ void k_q(const float* __restrict__ x0, const float* __restrict__ x1,
                    const float* __restrict__ Wq0, const float* __restrict__ Wq1,
                    float* __restrict__ qbuf, int N) {
    int id = blockIdx.x * blockDim.x + threadIdx.x;
    if (id >= N * CK) return;
    int n = id >> 4, k = id & 15;
    const float* x0n = x0 + (size_t)n * C;
    const float* x1n = x1 + (size_t)n * C * 3;
    float q0 = 0.f, q1a = 0.f, q1b = 0.f, q1c = 0.f;
#pragma unroll
    for (int c = 0; c < C; c++) {
        float w0 = Wq0[k * C + c], w1 = Wq1[k * C + c];
        q0  += w0 * x0n[c];
        q1a += w1 * x1n[c * 3 + 0];
        q1b += w1 * x1n[c * 3 + 1];
        q1c += w1 * x1n[c * 3 + 2];
    }
    float* qb = qbuf + (size_t)n * 64;
    qb[k] = q0;
    qb[16 + k * 3 + 0] = q1a;
    qb[16 + k * 3 + 1] = q1b;
    qb[16 + k * 3 + 2] = q1c;
}

// ---------------- K2: per-edge K construction + score + segment max + deg ----
__global__ __launch_bounds__(256) void k_score(
    const float* __restrict__ x0, const float* __restrict__ x1,
    const float* __restrict__ rel, const int* __restrict__ src, const int* __restrict__ dst,
    const float* __restrict__ Wr1, const float* __restrict__ br1,
    const float* __restrict__ Wr2, const float* __restrict__ br2,
    const float* __restrict__ Wk, const float* __restrict__ qbuf,
    float* __restrict__ scorebuf, unsigned* __restrict__ smax, float* __restrict__ degb,
    int E) {
    __shared__ float sWr2[RH * 160];
    __shared__ float sWk[NP * CK * C];
    __shared__ float sWr1[RH], sbr1[RH], sbr2K[80];
    __shared__ float sx0[16][C], sx1[16][C * 3], sq0[16][CK], sq1[16][CK * 3];
    __shared__ float st10[16][C];
    __shared__ float srh[16][4];
    int tid = threadIdx.x;
    for (int i = tid; i < RH * 160; i += 256) sWr2[i] = Wr2[i];
    for (int i = tid; i < NP * CK * C; i += 256) sWk[i] = Wk[i];
    if (tid < RH) { sWr1[tid] = Wr1[tid]; sbr1[tid] = br1[tid]; }
    if (tid < 80) sbr2K[tid] = br2[tid];

    int le = tid >> 4, k = tid & 15;
    int e = blockIdx.x * 16 + le;
    bool valid = e < E;
    int de = 0;
    if (valid) {
        int se = src[e];
        de = dst[e];
        sx0[le][k] = x0[(size_t)se * C + k];
#pragma unroll
        for (int m = 0; m < 3; m++) sx1[le][k * 3 + m] = x1[(size_t)se * C * 3 + k * 3 + m];
        sq0[le][k] = qbuf[(size_t)de * 64 + k];
#pragma unroll
        for (int m = 0; m < 3; m++) sq1[le][k * 3 + m] = qbuf[(size_t)de * 64 + 16 + k * 3 + m];
        if (k == 0) {
            float a = rel[(size_t)e * 3], b = rel[(size_t)e * 3 + 1], c = rel[(size_t)e * 3 + 2];
            float r = sqrtf(a * a + b * b + c * c);
            float inv = 1.f / (r + EPS);
            srh[le][0] = a * inv; srh[le][1] = b * inv; srh[le][2] = c * inv; srh[le][3] = r;
        }
    }
    __syncthreads();
    float rh0 = srh[le][0], rh1 = srh[le][1], rh2 = srh[le][2], r = srh[le][3];
    st10[le][k] = sx1[le][k * 3] * rh0 + sx1[le][k * 3 + 1] * rh1 + sx1[le][k * 3 + 2] * rh2;
    __syncthreads();

    float hR[RH];
#pragma unroll
    for (int h = 0; h < RH; h++) hR[h] = fmaxf(r * sWr1[h] + sbr1[h], 0.f);
    float radK[NP];
#pragma unroll
    for (int p = 0; p < NP; p++) {
        float acc = sbr2K[p * 16 + k];
#pragma unroll
        for (int h = 0; h < RH; h++) acc += hR[h] * sWr2[h * 160 + p * 16 + k];
        radK[p] = acc;
    }
    float u0 = 0, d1 = 0, u2 = 0, d4 = 0, w3a = 0, w3b = 0, w3c = 0;
#pragma unroll
    for (int c = 0; c < C; c++) {
        float xv = sx0[le][c], tv = st10[le][c];
        u0 += sWk[0 * 256 + k * 16 + c] * xv;
        d1 += sWk[1 * 256 + k * 16 + c] * xv;
        u2 += sWk[2 * 256 + k * 16 + c] * tv;
        d4 += sWk[4 * 256 + k * 16 + c] * tv;
        float w3 = sWk[3 * 256 + k * 16 + c];
        w3a += w3 * sx1[le][c * 3 + 0];
        w3b += w3 * sx1[le][c * 3 + 1];
        w3c += w3 * sx1[le][c * 3 + 2];
    }
    float k0  = radK[0] * u0 + radK[2] * u2;
    float k1a = radK[1] * rh0 * d1 + radK[3] * w3a + radK[4] * rh0 * d4;
    float k1b = radK[1] * rh1 * d1 + radK[3] * w3b + radK[4] * rh1 * d4;
    float k1c = radK[1] * rh2 * d1 + radK[3] * w3c + radK[4] * rh2 * d4;
    float s = sq0[le][k] * k0 + sq1[le][k * 3] * k1a + sq1[le][k * 3 + 1] * k1b +
              sq1[le][k * 3 + 2] * k1c;
    s += __shfl_xor(s, 1);
    if (valid && (k & 1) == 0) {
        int h = k >> 1;
        float sc = s * SCALE;
        scorebuf[(size_t)e * 8 + h] = sc;
        atomicMax(&smax[(size_t)de * 8 + h], fenc(sc));
    }
    if (valid && k == 0) atomicAdd(&degb[de], 1.0f);
}

// ---------------- K3: exp + segment denominator ----------------
__global__ void k_den(const int* __restrict__ dst, float* scorebuf,
                      const unsigned* __restrict__ smax, float* __restrict__ den, int EH) {
    int id = blockIdx.x * blockDim.x + threadIdx.x;
    if (id >= EH) return;
    int e = id >> 3, h = id & 7;
    int de = dst[e];
    float sc = scorebuf[id];
    float m = fdec(smax[(size_t)de * 8 + h]);
    float ex = expf(sc - m);
    scorebuf[id] = ex;  // reuse as exbuf
    atomicAdd(&den[(size_t)de * 8 + h], ex);
}

// ---------------- K4: per-edge V construction + alpha-weighted aggregation ----
__global__ __launch_bounds__(256) void k_av(
    const float* __restrict__ x0, const float* __restrict__ x1,
    const float* __restrict__ rel, const int* __restrict__ src, const int* __restrict__ dst,
    const float* __restrict__ Wr1, const float* __restrict__ br1,
    const float* __restrict__ Wr2, const float* __restrict__ br2,
    const float* __restrict__ Wv,
    const float* __restrict__ exbuf, const float* __restrict__ den,
    float* __restrict__ a0, float* __restrict__ a1, int E) {
    __shared__ float sWr2[RH * 160];
    __shared__ float sWv[NP * CK * C];
    __shared__ float sWr1[RH], sbr1[RH], sbr2V[80];
    __shared__ float sx0[16][C], sx1[16][C * 3], st10[16][C];
    __shared__ float srh[16][4];
    int tid = threadIdx.x;
    for (int i = tid; i < RH * 160; i += 256) sWr2[i] = Wr2[i];
    for (int i = tid; i < NP * CK * C; i += 256) sWv[i] = Wv[i];
    if (tid < RH) { sWr1[tid] = Wr1[tid]; sbr1[tid] = br1[tid]; }
    if (tid < 80) sbr2V[tid] = br2[80 + tid];

    int le = tid >> 4, k = tid & 15;
    int e = blockIdx.x * 16 + le;
    bool valid = e < E;
    int de = 0;
    if (valid) {
        int se = src[e];
        de = dst[e];
        sx0[le][k] = x0[(size_t)se * C + k];
#pragma unroll
        for (int m = 0; m < 3; m++) sx1[le][k * 3 + m] = x1[(size_t)se * C * 3 + k * 3 + m];
        if (k == 0) {
            float a = rel[(size_t)e * 3], b = rel[(size_t)e * 3 + 1], c = rel[(size_t)e * 3 + 2];
            float r = sqrtf(a * a + b * b + c * c);
            float inv = 1.f / (r + EPS);
            srh[le][0] = a * inv; srh[le][1] = b * inv; srh[le][2] = c * inv; srh[le][3] = r;
        }
    }
    __syncthreads();
    float rh0 = srh[le][0], rh1 = srh[le][1], rh2 = srh[le][2], r = srh[le][3];
    st10[le][k] = sx1[le][k * 3] * rh0 + sx1[le][k * 3 + 1] * rh1 + sx1[le][k * 3 + 2] * rh2;
    __syncthreads();

    float hR[RH];
#pragma unroll
    for (int h = 0; h < RH; h++) hR[h] = fmaxf(r * sWr1[h] + sbr1[h], 0.f);
    float radV[NP];
#pragma unroll
    for (int p = 0; p < NP; p++) {
        float acc = sbr2V[p * 16 + k];
#pragma unroll
        for (int h = 0; h < RH; h++) acc += hR[h] * sWr2[h * 160 + 80 + p * 16 + k];
        radV[p] = acc;
    }
    float u0 = 0, d1 = 0, u2 = 0, d4 = 0, w3a = 0, w3b = 0, w3c = 0;
#pragma unroll
    for (int c = 0; c < C; c++) {
        float xv = sx0[le][c], tv = st10[le][c];
        u0 += sWv[0 * 256 + k * 16 + c] * xv;
        d1 += sWv[1 * 256 + k * 16 + c] * xv;
        u2 += sWv[2 * 256 + k * 16 + c] * tv;
        d4 += sWv[4 * 256 + k * 16 + c] * tv;
        float w3 = sWv[3 * 256 + k * 16 + c];
        w3a += w3 * sx1[le][c * 3 + 0];
        w3b += w3 * sx1[le][c * 3 + 1];
        w3c += w3 * sx1[le][c * 3 + 2];
    }
    float v0  = radV[0] * u0 + radV[2] * u2;
    float v1a = radV[1] * rh0 * d1 + radV[3] * w3a + radV[4] * rh0 * d4;
    float v1b = radV[1] * rh1 * d1 + radV[3] * w3b + radV[4] * rh1 * d4;
    float v1c = radV[1] * rh2 * d1 + radV[3] * w3c + radV[4] * rh2 * d4;
    if (valid) {
        int h = k >> 1;
        float ex = exbuf[(size_t)e * 8 + h];
        float dn = den[(size_t)de * 8 + h];
        float alpha = ex / (dn + EPS);
        atomicAdd(&a0[(size_t)de * 16 + k], alpha * v0);
        atomicAdd(&a1[(size_t)de * 48 + k * 3 + 0], alpha * v1a);
        atomicAdd(&a1[(size_t)de * 48 + k * 3 + 1], alpha * v1b);
        atomicAdd(&a1[(size_t)de * 48 + k * 3 + 2], alpha * v1c);
    }
}

// ---------------- K5: per-node h0/h1 projections ----------------
__global__ void k_h(const float* __restrict__ x0, const float* __restrict__ x1,
                    const float* __restrict__ a0, const float* __restrict__ a1,
                    const float* __restrict__ Wp0, const float* __restrict__ Wp1,
                    float* __restrict__ h0buf, float* __restrict__ h1buf, int N) {
    int id = blockIdx.x * blockDim.x + threadIdx.x;
    if (id >= N * C) return;
    int n = id >> 4, c = id & 15;
    float h0 = 0, h1a = 0, h1b = 0, h1c = 0;
#pragma unroll
    for (int j = 0; j < 16; j++) {
        float wa = Wp0[c * 32 + j], wx = Wp0[c * 32 + 16 + j];
        h0 += wa * a0[(size_t)n * 16 + j] + wx * x0[(size_t)n * 16 + j];
        float va = Wp1[c * 32 + j], vx = Wp1[c * 32 + 16 + j];
        h1a += va * a1[(size_t)n * 48 + j * 3 + 0] + vx * x1[(size_t)n * 48 + j * 3 + 0];
        h1b += va * a1[(size_t)n * 48 + j * 3 + 1] + vx * x1[(size_t)n * 48 + j * 3 + 1];
        h1c += va * a1[(size_t)n * 48 + j * 3 + 2] + vx * x1[(size_t)n * 48 + j * 3 + 2];
    }
    h0buf[(size_t)n * 16 + c] = h0;
    h1buf[(size_t)n * 48 + c * 3 + 0] = h1a;
    h1buf[(size_t)n * 48 + c * 3 + 1] = h1b;
    h1buf[(size_t)n * 48 + c * 3 + 2] = h1c;
}

// ---------------- K6: per-edge m0 + aggregation ----------------
__global__ __launch_bounds__(256) void k_m(
    const float* __restrict__ rel, const int* __restrict__ src, const int* __restrict__ dst,
    const float* __restrict__ Wr1, const float* __restrict__ br1,
    const float* __restrict__ Wrf, const float* __restrict__ brf,
    const float* __restrict__ Wf, const float* __restrict__ Wf1,
    const float* __restrict__ h0buf, const float* __restrict__ h1buf,
    float* __restrict__ agg, int E) {
    __shared__ float sh0[8][16], sh1[8][48], st10[8][16], srh[8][4];
    int tid = threadIdx.x;
    int le = tid >> 5, o = tid & 31;
    int e = blockIdx.x * 8 + le;
    bool valid = e < E;
    int de = 0;
    if (valid) {
        int se = src[e];
        de = dst[e];
        if (o < 16) sh0[le][o] = h0buf[(size_t)se * 16 + o];
        sh1[le][o] = h1buf[(size_t)se * 48 + o];
        if (o < 16) sh1[le][32 + o] = h1buf[(size_t)se * 48 + 32 + o];
        if (o == 0) {
            float a = rel[(size_t)e * 3], b = rel[(size_t)e * 3 + 1], c = rel[(size_t)e * 3 + 2];
            float r = sqrtf(a * a + b * b + c * c);
            float inv = 1.f / (r + EPS);
            srh[le][0] = a * inv; srh[le][1] = b * inv; srh[le][2] = c * inv; srh[le][3] = r;
        }
    }
    __syncthreads();
    if (o < 16)
        st10[le][o] = sh1[le][o * 3] * srh[le][0] + sh1[le][o * 3 + 1] * srh[le][1] +
                      sh1[le][o * 3 + 2] * srh[le][2];
    __syncthreads();
    float r = srh[le][3];
    float radF = brf[o];
#pragma unroll
    for (int h = 0; h < RH; h++) {
        float hR = fmaxf(r * Wr1[h] + br1[h], 0.f);
        radF += hR * Wrf[h * 32 + o];
    }
    float d = 0;
#pragma unroll
    for (int c = 0; c < C; c++)
        d += Wf[o * 16 + c] * sh0[le][c] + Wf1[o * 16 + c] * st10[le][c];
    if (valid) atomicAdd(&agg[(size_t)de * 32 + o], radF * d);
}

// ---------------- K7: final output ----------------
__global__ void k_out(const float* __restrict__ h0buf, const float* __restrict__ agg,
                      const float* __restrict__ degb, const float* __restrict__ Wself0,
                      float* __restrict__ out, int N) {
    int id = blockIdx.x * blockDim.x + threadIdx.x;
    if (id >= N * 32) return;
    int n = id >> 5, o = id & 31;
    float acc = agg[id] / fmaxf(degb[n], 1.0f);
#pragma unroll
    for (int c = 0; c < C; c++) acc += Wself0[o * 16 + c] * h0buf[(size_t)n * 16 + c];
    out[id] = acc;
}

extern "C" void kernel_launch(void* const* d_in, const int* in_sizes, int n_in,
                              void* d_out, int out_size, void* d_ws, size_t ws_size,
                              hipStream_t stream) {
    const float* x0  = (const float*)d_in[0];
    const float* x1  = (const float*)d_in[1];
    const float* rel = (const float*)d_in[2];
    const int* src   = (const int*)d_in[3];
    const int* dst   = (const int*)d_in[4];
    const float* Wr1 = (const float*)d_in[5];
    const float* br1 = (const float*)d_in[6];
    const float* Wr2 = (const float*)d_in[7];
    const float* br2 = (const float*)d_in[8];
    const float* Wk  = (const float*)d_in[9];
    const float* Wv  = (const float*)d_in[10];
    const float* Wq0 = (const float*)d_in[11];
    const float* Wq1 = (const float*)d_in[12];
    const float* Wp0 = (const float*)d_in[13];
    const float* Wp1 = (const float*)d_in[14];
    const float* Wrf = (const float*)d_in[15];
    const float* brf = (const float*)d_in[16];
    const float* Wf  = (const float*)d_in[17];
    const float* Wf1 = (const float*)d_in[18];
    const float* Wself0 = (const float*)d_in[19];

    int N = in_sizes[0] / C;   // x0 is N*C*1
    int E = in_sizes[2] / 3;   // rel_pos is E*3

    float* ws = (float*)d_ws;
    float* qbuf     = ws;                           // N*64
    float* scorebuf = qbuf + (size_t)N * 64;        // E*8 (reused as exbuf)
    float* accbase  = scorebuf + (size_t)E * 8;     // zeroed region start
    unsigned* smax  = (unsigned*)accbase;           // N*8
    float* den      = accbase + (size_t)N * 8;      // N*8
    float* a0       = den + (size_t)N * 8;          // N*16
    float* a1       = a0 + (size_t)N * 16;          // N*48
    float* agg      = a1 + (size_t)N * 48;          // N*32
    float* degb     = agg + (size_t)N * 32;         // N
    float* h0buf    = degb + N;                     // N*16
    float* h1buf    = h0buf + (size_t)N * 16;       // N*48

    // zero the accumulator region (smax encoding: 0 == "-inf")
    hipMemsetAsync(accbase, 0, (size_t)N * 113 * sizeof(float), stream);

    k_q<<<(N * 16 + 255) / 256, 256, 0, stream>>>(x0, x1, Wq0, Wq1, qbuf, N);
    k_score<<<(E + 15) / 16, 256, 0, stream>>>(x0, x1, rel, src, dst, Wr1, br1, Wr2, br2,
                                               Wk, qbuf, scorebuf, smax, degb, E);
    k_den<<<(E * 8 + 255) / 256, 256, 0, stream>>>(dst, scorebuf, smax, den, E * 8);
    k_av<<<(E + 15) / 16, 256, 0, stream>>>(x0, x1, rel, src, dst, Wr1, br1, Wr2, br2,
                                            Wv, scorebuf, den, a0, a1, E);
    k_h<<<(N * 16 + 255) / 256, 256, 0, stream>>>(x0, x1, a0, a1, Wp0, Wp1, h0buf, h1buf, N);
    k_m<<<(E + 7) / 8, 256, 0, stream>>>(rel, src, dst, Wr1, br1, Wrf, brf, Wf, Wf1,
                                         h0buf, h1buf, agg, E);
    k_out<<<(N * 32 + 255) / 256, 256, 0, stream>>>(h0buf, agg, degb, Wself0, (float*)d_out, N);
}